// Round 6
// baseline (927.787 us; speedup 1.0000x reference)
//
#include <hip/hip_runtime.h>
#include <hip/hip_bf16.h>

// Gramba (fp32 in / fp32 out): x_in = silu(x@W1+b1); x_skip = silu(x@W2+b2)
//         z = sigmoid(x_in@Wz+bz); h~ = x_in@Wh+bh
//         h = scan(h = (1-z)h + z*h~); out = (x_skip+h)@Wo + bo
// R6: XOR-swizzled LDS (kills 8-way ds_read bank conflicts); W1|W2 merged
// input GEMM (split-silu epilogue); Wz|Wh merged chunk GEMM writing raw
// pre-activations; scan applies sigmoid / z*h~ inline.
//
// Workspace layout (183 MiB):
//   [0,32)    rawzh chunk (bf16, 4096x4096)   [xb overlays [0,16) before use]
//   [32,33)   carry (fp32 h state, 4x2048)
//   [33,97)   xin   (bf16, 16384x2048)
//   [97,161)  xskip (bf16; scan overwrites with s = x_skip+h)
//   [161,165) Wt12  (bf16 [4096][512]:  W1^T rows 0..2047, W2^T rows 2048..)
//   [165,181) Wtzh  (bf16 [4096][2048]: Wz^T, Wh^T)
//   [181,183) Wto   (bf16 [512][2048])

typedef __bf16 bf16x8 __attribute__((ext_vector_type(8)));
typedef __bf16 bf16x4 __attribute__((ext_vector_type(4)));
typedef float  f32x4  __attribute__((ext_vector_type(4)));

#define DEVINL __device__ __forceinline__

DEVINL void async_ld16(const __bf16* g, __bf16* l) {
    __builtin_amdgcn_global_load_lds(
        (const __attribute__((address_space(1))) void*)g,
        (__attribute__((address_space(3))) void*)l, 16, 0, 0);
}

DEVINL float fsigmoid(float v) { return 1.0f / (1.0f + __expf(-v)); }

// MODE 0: dual split-silu -> bf16 out/out2 (row stride 2048 each, cols 0..4095)
// MODE 3: fp32 single out, stride N
// MODE 4: plain bf16 single out, stride N, dual bias (split at 2048)
// LDS swizzle: global (row,kc) stored at slot kc^((row>>1)&3); read side XORs
// the same term -> each bank hit exactly 2x per wave access (conflict-free).
template <int MODE>
__global__ __launch_bounds__(256)
void gemm_bt(const __bf16* __restrict__ A, const __bf16* __restrict__ Bt,
             const float* __restrict__ bias, const float* __restrict__ bias2,
             void* __restrict__ out, void* __restrict__ out2, int N, int K,
             int bps, int seg_stride, int row_off)
{
    __shared__ __bf16 As[128 * 32];
    __shared__ __bf16 Bs[128 * 32];
    const int tid = threadIdx.x;
    const int bx = blockIdx.x;
    const int seg = bx / bps;
    const int within = bx - seg * bps;
    const int gm0 = row_off + seg * seg_stride + within * 128;  // A row base
    const int om0 = bx * 128;                                   // out row base
    const int n0 = blockIdx.y * 128;

    // Staging: 8KB tile = 512 x 16B chunks. Slot c holds global chunk
    // (row = c>>2, kc = (c&3) ^ ((c>>3)&3)).
    const int c0 = tid, c1 = tid + 256;
    const int r0 = c0 >> 2, k0 = (c0 & 3) ^ ((c0 >> 3) & 3);
    const int r1 = c1 >> 2, k1 = (c1 & 3) ^ ((c1 >> 3) & 3);
    const __bf16* Ag0 = A  + (size_t)(gm0 + r0) * K + k0 * 8;
    const __bf16* Ag1 = A  + (size_t)(gm0 + r1) * K + k1 * 8;
    const __bf16* Bg0 = Bt + (size_t)(n0 + r0) * K + k0 * 8;
    const __bf16* Bg1 = Bt + (size_t)(n0 + r1) * K + k1 * 8;
    __bf16* Al0 = As + c0 * 8;
    __bf16* Al1 = As + c1 * 8;
    __bf16* Bl0 = Bs + c0 * 8;
    __bf16* Bl1 = Bs + c1 * 8;

    const int lane = tid & 63;
    const int wave = tid >> 6;
    const int wrow = (wave >> 1) * 64;
    const int wcol = (wave & 1) * 64;
    const int quad = lane >> 4;
    const int r = lane & 15;
    // swizzled k-slot for this lane's fragment reads (row parity = r parity)
    const int swz = (quad ^ ((r >> 1) & 3)) * 8;

    f32x4 acc[4][4] = {};

    for (int kt = 0; kt < K; kt += 32) {
        __syncthreads();
        async_ld16(Ag0 + kt, Al0);
        async_ld16(Ag1 + kt, Al1);
        async_ld16(Bg0 + kt, Bl0);
        async_ld16(Bg1 + kt, Bl1);
        __syncthreads();

        const __bf16* ap = As + (wrow + r) * 32 + swz;
        const __bf16* bp = Bs + (wcol + r) * 32 + swz;
        bf16x8 af[4], bf_[4];
#pragma unroll
        for (int i = 0; i < 4; ++i) af[i] = *(const bf16x8*)(ap + i * 512);
#pragma unroll
        for (int i = 0; i < 4; ++i) bf_[i] = *(const bf16x8*)(bp + i * 512);
#pragma unroll
        for (int i = 0; i < 4; ++i)
#pragma unroll
            for (int j = 0; j < 4; ++j)
                acc[i][j] = __builtin_amdgcn_mfma_f32_16x16x32_bf16(
                    af[i], bf_[j], acc[i][j], 0, 0, 0);
    }

    // C/D layout (m89): col = lane&15, row = (lane>>4)*4 + reg
#pragma unroll
    for (int i = 0; i < 4; ++i) {
#pragma unroll
        for (int j = 0; j < 4; ++j) {
            const int or0 = om0 + wrow + i * 16 + quad * 4;
            const int gc  = n0 + wcol + j * 16 + r;
            const bool lo = gc < 2048;
            const float bv = (MODE == 3) ? bias[gc]
                           : (lo ? bias[gc] : bias2[gc - 2048]);
#pragma unroll
            for (int k = 0; k < 4; ++k) {
                const float v = acc[i][j][k] + bv;
                if (MODE == 0) {
                    __bf16* dst = lo ? (__bf16*)out : (__bf16*)out2;
                    const int cc = lo ? gc : gc - 2048;
                    dst[(size_t)(or0 + k) * 2048 + cc] = (__bf16)(v * fsigmoid(v));
                } else if (MODE == 4) {
                    ((__bf16*)out)[(size_t)(or0 + k) * N + gc] = (__bf16)v;
                } else {
                    ((float*)out)[(size_t)(or0 + k) * N + gc] = v;
                }
            }
        }
    }
}

// Parallel minGRU scan over one chunk, on raw pre-activations:
// z = sigmoid(raw_z), b = z * raw_h, h = (1-z)h + b.
// raw is [B*CS][4096] (z cols 0..2047, h cols 2048..4095).
// Block = 64 channels (lane) x 16 waves (64-step segments); 2-phase affine scan.
#define SCAN_WAVES 16
__global__ __launch_bounds__(1024)
void scan_kernel(const __bf16* __restrict__ raw, __bf16* __restrict__ xskip,
                 float* __restrict__ carry, int CS, int S, int t0, int first)
{
    __shared__ float Als[SCAN_WAVES][64];
    __shared__ float Bls[SCAN_WAVES][64];
    const int lane = threadIdx.x & 63;
    const int w = threadIdx.x >> 6;
    const int gpb = 2048 >> 6;                 // 32 channel groups per batch
    const int batch = blockIdx.x / gpb;
    const int col = (blockIdx.x - batch * gpb) * 64 + lane;
    const int L = CS / SCAN_WAVES;             // 64
    const int tbeg = w * L;

    const size_t rbase = ((size_t)batch * CS + tbeg) * 4096 + col;

    // Phase 1: segment aggregate (A, B)
    float A = 1.0f, Bv = 0.0f;
    {
        size_t idx = rbase;
#pragma unroll 8
        for (int t = 0; t < L; ++t, idx += 4096) {
            const float z = fsigmoid((float)raw[idx]);
            const float b = z * (float)raw[idx + 2048];
            const float a = 1.0f - z;
            Bv = a * Bv + b;
            A *= a;
        }
    }
    Als[w][lane] = A;
    Bls[w][lane] = Bv;
    __syncthreads();

    // Exact fp32 prefix: h at this wave's segment start
    const int ch = batch * 2048 + col;
    float h = first ? 0.0f : carry[ch];
    for (int s = 0; s < w; ++s)
        h = Als[s][lane] * h + Bls[s][lane];
    if (w == SCAN_WAVES - 1)
        carry[ch] = A * h + Bv;   // chunk-final state

    // Phase 2: re-walk with true h_start, emit s = x_skip + h (in place)
    {
        size_t idx = rbase;
        size_t gidx = ((size_t)batch * S + t0 + tbeg) * 2048 + col;
#pragma unroll 8
        for (int t = 0; t < L; ++t, idx += 4096, gidx += 2048) {
            const float z = fsigmoid((float)raw[idx]);
            const float b = z * (float)raw[idx + 2048];
            h = (1.0f - z) * h + b;
            xskip[gidx] = (__bf16)((float)xskip[gidx] + h);
        }
    }
}

__global__ __launch_bounds__(256)
void conv_f32_bf16(const float* __restrict__ x, __bf16* __restrict__ y, int n4)
{
    const int i = blockIdx.x * 256 + threadIdx.x;
    if (i >= n4) return;
    const float4 v = ((const float4*)x)[i];
    bf16x4 o;
    o[0] = (__bf16)v.x; o[1] = (__bf16)v.y; o[2] = (__bf16)v.z; o[3] = (__bf16)v.w;
    ((bf16x4*)y)[i] = o;
}

// W[K][N] fp32 -> Wt[N][K] bf16
__global__ __launch_bounds__(256)
void transpose_bf16(const float* __restrict__ W, __bf16* __restrict__ Wt, int K, int N)
{
    __shared__ float tile[32][33];
    const int tx = threadIdx.x & 31;
    const int ty = threadIdx.x >> 5;   // 0..7
    const int nb = blockIdx.x * 32;
    const int kb = blockIdx.y * 32;
#pragma unroll
    for (int i = 0; i < 32; i += 8)
        tile[ty + i][tx] = W[(size_t)(kb + ty + i) * N + nb + tx];
    __syncthreads();
#pragma unroll
    for (int i = 0; i < 32; i += 8)
        Wt[(size_t)(nb + ty + i) * K + kb + tx] = (__bf16)tile[tx][ty + i];
}

extern "C" void kernel_launch(void* const* d_in, const int* in_sizes, int n_in,
                              void* d_out, int out_size, void* d_ws, size_t ws_size,
                              hipStream_t stream)
{
    const float* x     = (const float*)d_in[0];
    const float* W_in1 = (const float*)d_in[1];
    const float* b_in1 = (const float*)d_in[2];
    const float* W_in2 = (const float*)d_in[3];
    const float* b_in2 = (const float*)d_in[4];
    const float* W_z   = (const float*)d_in[5];
    const float* b_z   = (const float*)d_in[6];
    const float* W_h   = (const float*)d_in[7];
    const float* b_h   = (const float*)d_in[8];
    const float* W_out = (const float*)d_in[9];
    const float* b_out = (const float*)d_in[10];

    const int B = 4, S = 4096, H = 512, E = 2048;
    const int M = B * S;        // 16384
    const int CS = 1024;        // chunk length
    const int NC = S / CS;      // 4 chunks
    const int MC = B * CS;      // 4096 rows per chunk

    const size_t MiB = 1024 * 1024;
    const size_t NEEDED = 183 * MiB;
    if (ws_size < NEEDED) return;   // diagnostic fail (absmax == max|ref|)

    char* ws = (char*)d_ws;
    __bf16* xb    = (__bf16*)(ws + 0);        // overlaid by rawzh after use
    __bf16* rawzh = (__bf16*)(ws + 0);
    float*  carry = (float*) (ws + 32 * MiB);
    __bf16* xin   = (__bf16*)(ws + 33 * MiB);
    __bf16* xskip = (__bf16*)(ws + 97 * MiB);
    __bf16* Wt12  = (__bf16*)(ws + 161 * MiB);
    __bf16* Wtzh  = (__bf16*)(ws + 165 * MiB);
    __bf16* Wto   = (__bf16*)(ws + 181 * MiB);

    conv_f32_bf16<<<(M * H / 4 + 255) / 256, 256, 0, stream>>>(x, xb, M * H / 4);
    // Concatenated transposed weights
    transpose_bf16<<<dim3(E / 32, H / 32), 256, 0, stream>>>(W_in1, Wt12, H, E);
    transpose_bf16<<<dim3(E / 32, H / 32), 256, 0, stream>>>(W_in2, Wt12 + (size_t)E * H, H, E);
    transpose_bf16<<<dim3(E / 32, E / 32), 256, 0, stream>>>(W_z, Wtzh, E, E);
    transpose_bf16<<<dim3(E / 32, E / 32), 256, 0, stream>>>(W_h, Wtzh + (size_t)E * E, E, E);
    transpose_bf16<<<dim3(H / 32, E / 32), 256, 0, stream>>>(W_out, Wto, E, H);

    // Merged input GEMM: N=4096 (W1|W2), split-silu epilogue -> xin / xskip
    gemm_bt<0><<<dim3(M / 128, 2 * E / 128), 256, 0, stream>>>(
        xb, Wt12, b_in1, b_in2, xin, xskip, 2 * E, H, M / 128, 0, 0);

    // Recurrent stage, chunked over S (rawzh overlays dead xb)
    for (int c = 0; c < NC; ++c) {
        const int row_off = c * CS;
        gemm_bt<4><<<dim3(MC / 128, 2 * E / 128), 256, 0, stream>>>(
            xin, Wtzh, b_z, b_h, rawzh, nullptr, 2 * E, E, CS / 128, S, row_off);
        scan_kernel<<<(B * E) / 64, 1024, 0, stream>>>(
            rawzh, xskip, carry, CS, S, row_off, c == 0);
    }

    // Output GEMM (full M), fp32 out
    gemm_bt<3><<<dim3(M / 128, H / 128), 256, 0, stream>>>(
        xskip, Wto, b_out, nullptr, (float*)d_out, nullptr, H, E, M / 128, 0, 0);
}

// Round 7
// 899.466 us; speedup vs baseline: 1.0315x; 1.0315x over previous
//
#include <hip/hip_runtime.h>
#include <hip/hip_bf16.h>

// Gramba (fp32 in / fp32 out): x_in = silu(x@W1+b1); x_skip = silu(x@W2+b2)
//         z = sigmoid(x_in@Wz+bz); h~ = x_in@Wh+bh
//         h = scan(h = (1-z)h + z*h~); out = (x_skip+h)@Wo + bo
// R7: double-buffered LDS K-loop with raw s_barrier + manual vmcnt(4) --
// prefetch loads stay in flight across the barrier (AITER pattern); no
// __syncthreads -> no compiler vmcnt(0) drain. XOR-swizzled LDS (0 conflicts).
// Merged W1|W2 input GEMM, merged Wz|Wh chunk GEMM, 2-phase affine scan.
//
// Workspace layout (183 MiB):
//   [0,32)    rawzh chunk (bf16, 4096x4096)   [xb overlays [0,16) before use]
//   [32,33)   carry (fp32 h state, 4x2048)
//   [33,97)   xin   (bf16, 16384x2048)
//   [97,161)  xskip (bf16; scan overwrites with s = x_skip+h)
//   [161,165) Wt12  (bf16 [4096][512])
//   [165,181) Wtzh  (bf16 [4096][2048])
//   [181,183) Wto   (bf16 [512][2048])

typedef __bf16 bf16x8 __attribute__((ext_vector_type(8)));
typedef __bf16 bf16x4 __attribute__((ext_vector_type(4)));
typedef float  f32x4  __attribute__((ext_vector_type(4)));

#define DEVINL __device__ __forceinline__

DEVINL void async_ld16(const __bf16* g, __bf16* l) {
    __builtin_amdgcn_global_load_lds(
        (const __attribute__((address_space(1))) void*)g,
        (__attribute__((address_space(3))) void*)l, 16, 0, 0);
}

DEVINL float fsigmoid(float v) { return 1.0f / (1.0f + __expf(-v)); }

// MODE 0: dual split-silu -> bf16 out/out2 | MODE 3: fp32 out | MODE 4: bf16 out
// LDS swizzle: global (row,kc) stored at slot kc^((row>>1)&3); read side XORs
// the same -> conflict-free (verified R6: SQ_LDS_BANK_CONFLICT = 0).
template <int MODE>
__global__ __launch_bounds__(256)
void gemm_bt(const __bf16* __restrict__ A, const __bf16* __restrict__ Bt,
             const float* __restrict__ bias, const float* __restrict__ bias2,
             void* __restrict__ out, void* __restrict__ out2, int N, int K,
             int bps, int seg_stride, int row_off)
{
    __shared__ __bf16 As[2][128 * 32];
    __shared__ __bf16 Bs[2][128 * 32];
    const int tid = threadIdx.x;
    const int bx = blockIdx.x;
    const int seg = bx / bps;
    const int within = bx - seg * bps;
    const int gm0 = row_off + seg * seg_stride + within * 128;  // A row base
    const int om0 = bx * 128;                                   // out row base
    const int n0 = blockIdx.y * 128;

    // Staging: 8KB tile = 512 x 16B chunks. Slot c holds global chunk
    // (row = c>>2, kc = (c&3) ^ ((c>>3)&3)).
    const int c0 = tid, c1 = tid + 256;
    const int r0 = c0 >> 2, k0 = (c0 & 3) ^ ((c0 >> 3) & 3);
    const int r1 = c1 >> 2, k1 = (c1 & 3) ^ ((c1 >> 3) & 3);
    const __bf16* Ag0 = A  + (size_t)(gm0 + r0) * K + k0 * 8;
    const __bf16* Ag1 = A  + (size_t)(gm0 + r1) * K + k1 * 8;
    const __bf16* Bg0 = Bt + (size_t)(n0 + r0) * K + k0 * 8;
    const __bf16* Bg1 = Bt + (size_t)(n0 + r1) * K + k1 * 8;

    const int lane = tid & 63;
    const int wave = tid >> 6;
    const int wrow = (wave >> 1) * 64;
    const int wcol = (wave & 1) * 64;
    const int quad = lane >> 4;
    const int r = lane & 15;
    const int swz = (quad ^ ((r >> 1) & 3)) * 8;

    f32x4 acc[4][4] = {};

    const int T = K >> 5;
    // Prefetch tile 0 into buffer 0
    async_ld16(Ag0, As[0] + c0 * 8);
    async_ld16(Ag1, As[0] + c1 * 8);
    async_ld16(Bg0, Bs[0] + c0 * 8);
    async_ld16(Bg1, Bs[0] + c1 * 8);

    for (int t = 0; t < T; ++t) {
        const int cur = t & 1;
        if (t + 1 < T) {
            const int kt = (t + 1) << 5;
            // Issue next tile's loads into the other buffer (its readers
            // finished at the end-of-iter barrier of t-1), then wait only
            // for THIS tile's 4 loads: 8 outstanding -> wait to 4.
            async_ld16(Ag0 + kt, As[cur ^ 1] + c0 * 8);
            async_ld16(Ag1 + kt, As[cur ^ 1] + c1 * 8);
            async_ld16(Bg0 + kt, Bs[cur ^ 1] + c0 * 8);
            async_ld16(Bg1 + kt, Bs[cur ^ 1] + c1 * 8);
            asm volatile("s_waitcnt vmcnt(4)\n\ts_barrier" ::: "memory");
        } else {
            asm volatile("s_waitcnt vmcnt(0)\n\ts_barrier" ::: "memory");
        }

        const __bf16* ap = As[cur] + (wrow + r) * 32 + swz;
        const __bf16* bp = Bs[cur] + (wcol + r) * 32 + swz;
        bf16x8 af[4], bf_[4];
#pragma unroll
        for (int i = 0; i < 4; ++i) af[i] = *(const bf16x8*)(ap + i * 512);
#pragma unroll
        for (int i = 0; i < 4; ++i) bf_[i] = *(const bf16x8*)(bp + i * 512);
#pragma unroll
        for (int i = 0; i < 4; ++i)
#pragma unroll
            for (int j = 0; j < 4; ++j)
                acc[i][j] = __builtin_amdgcn_mfma_f32_16x16x32_bf16(
                    af[i], bf_[j], acc[i][j], 0, 0, 0);

        // Readers done (lgkm drained) before next iter overwrites this buffer.
        asm volatile("s_waitcnt lgkmcnt(0)\n\ts_barrier" ::: "memory");
    }

    // C/D layout (m89): col = lane&15, row = (lane>>4)*4 + reg
#pragma unroll
    for (int i = 0; i < 4; ++i) {
#pragma unroll
        for (int j = 0; j < 4; ++j) {
            const int or0 = om0 + wrow + i * 16 + quad * 4;
            const int gc  = n0 + wcol + j * 16 + r;
            const bool lo = gc < 2048;
            const float bv = (MODE == 3) ? bias[gc]
                           : (lo ? bias[gc] : bias2[gc - 2048]);
#pragma unroll
            for (int k = 0; k < 4; ++k) {
                const float v = acc[i][j][k] + bv;
                if (MODE == 0) {
                    __bf16* dst = lo ? (__bf16*)out : (__bf16*)out2;
                    const int cc = lo ? gc : gc - 2048;
                    dst[(size_t)(or0 + k) * 2048 + cc] = (__bf16)(v * fsigmoid(v));
                } else if (MODE == 4) {
                    ((__bf16*)out)[(size_t)(or0 + k) * N + gc] = (__bf16)v;
                } else {
                    ((float*)out)[(size_t)(or0 + k) * N + gc] = v;
                }
            }
        }
    }
}

// Parallel minGRU scan over one chunk, on raw pre-activations:
// z = sigmoid(raw_z), b = z * raw_h, h = (1-z)h + b.
// raw is [B*CS][4096] (z cols 0..2047, h cols 2048..4095).
#define SCAN_WAVES 16
__global__ __launch_bounds__(1024)
void scan_kernel(const __bf16* __restrict__ raw, __bf16* __restrict__ xskip,
                 float* __restrict__ carry, int CS, int S, int t0, int first)
{
    __shared__ float Als[SCAN_WAVES][64];
    __shared__ float Bls[SCAN_WAVES][64];
    const int lane = threadIdx.x & 63;
    const int w = threadIdx.x >> 6;
    const int gpb = 2048 >> 6;
    const int batch = blockIdx.x / gpb;
    const int col = (blockIdx.x - batch * gpb) * 64 + lane;
    const int L = CS / SCAN_WAVES;             // 64
    const int tbeg = w * L;

    const size_t rbase = ((size_t)batch * CS + tbeg) * 4096 + col;

    float A = 1.0f, Bv = 0.0f;
    {
        size_t idx = rbase;
#pragma unroll 8
        for (int t = 0; t < L; ++t, idx += 4096) {
            const float z = fsigmoid((float)raw[idx]);
            const float b = z * (float)raw[idx + 2048];
            const float a = 1.0f - z;
            Bv = a * Bv + b;
            A *= a;
        }
    }
    Als[w][lane] = A;
    Bls[w][lane] = Bv;
    __syncthreads();

    const int ch = batch * 2048 + col;
    float h = first ? 0.0f : carry[ch];
    for (int s = 0; s < w; ++s)
        h = Als[s][lane] * h + Bls[s][lane];
    if (w == SCAN_WAVES - 1)
        carry[ch] = A * h + Bv;

    {
        size_t idx = rbase;
        size_t gidx = ((size_t)batch * S + t0 + tbeg) * 2048 + col;
#pragma unroll 8
        for (int t = 0; t < L; ++t, idx += 4096, gidx += 2048) {
            const float z = fsigmoid((float)raw[idx]);
            const float b = z * (float)raw[idx + 2048];
            h = (1.0f - z) * h + b;
            xskip[gidx] = (__bf16)((float)xskip[gidx] + h);
        }
    }
}

__global__ __launch_bounds__(256)
void conv_f32_bf16(const float* __restrict__ x, __bf16* __restrict__ y, int n4)
{
    const int i = blockIdx.x * 256 + threadIdx.x;
    if (i >= n4) return;
    const float4 v = ((const float4*)x)[i];
    bf16x4 o;
    o[0] = (__bf16)v.x; o[1] = (__bf16)v.y; o[2] = (__bf16)v.z; o[3] = (__bf16)v.w;
    ((bf16x4*)y)[i] = o;
}

// W[K][N] fp32 -> Wt[N][K] bf16
__global__ __launch_bounds__(256)
void transpose_bf16(const float* __restrict__ W, __bf16* __restrict__ Wt, int K, int N)
{
    __shared__ float tile[32][33];
    const int tx = threadIdx.x & 31;
    const int ty = threadIdx.x >> 5;
    const int nb = blockIdx.x * 32;
    const int kb = blockIdx.y * 32;
#pragma unroll
    for (int i = 0; i < 32; i += 8)
        tile[ty + i][tx] = W[(size_t)(kb + ty + i) * N + nb + tx];
    __syncthreads();
#pragma unroll
    for (int i = 0; i < 32; i += 8)
        Wt[(size_t)(nb + ty + i) * K + kb + tx] = (__bf16)tile[tx][ty + i];
}

extern "C" void kernel_launch(void* const* d_in, const int* in_sizes, int n_in,
                              void* d_out, int out_size, void* d_ws, size_t ws_size,
                              hipStream_t stream)
{
    const float* x     = (const float*)d_in[0];
    const float* W_in1 = (const float*)d_in[1];
    const float* b_in1 = (const float*)d_in[2];
    const float* W_in2 = (const float*)d_in[3];
    const float* b_in2 = (const float*)d_in[4];
    const float* W_z   = (const float*)d_in[5];
    const float* b_z   = (const float*)d_in[6];
    const float* W_h   = (const float*)d_in[7];
    const float* b_h   = (const float*)d_in[8];
    const float* W_out = (const float*)d_in[9];
    const float* b_out = (const float*)d_in[10];

    const int B = 4, S = 4096, H = 512, E = 2048;
    const int M = B * S;        // 16384
    const int CS = 1024;        // chunk length
    const int NC = S / CS;      // 4 chunks
    const int MC = B * CS;      // 4096 rows per chunk

    const size_t MiB = 1024 * 1024;
    const size_t NEEDED = 183 * MiB;
    if (ws_size < NEEDED) return;

    char* ws = (char*)d_ws;
    __bf16* xb    = (__bf16*)(ws + 0);        // overlaid by rawzh after use
    __bf16* rawzh = (__bf16*)(ws + 0);
    float*  carry = (float*) (ws + 32 * MiB);
    __bf16* xin   = (__bf16*)(ws + 33 * MiB);
    __bf16* xskip = (__bf16*)(ws + 97 * MiB);
    __bf16* Wt12  = (__bf16*)(ws + 161 * MiB);
    __bf16* Wtzh  = (__bf16*)(ws + 165 * MiB);
    __bf16* Wto   = (__bf16*)(ws + 181 * MiB);

    conv_f32_bf16<<<(M * H / 4 + 255) / 256, 256, 0, stream>>>(x, xb, M * H / 4);
    transpose_bf16<<<dim3(E / 32, H / 32), 256, 0, stream>>>(W_in1, Wt12, H, E);
    transpose_bf16<<<dim3(E / 32, H / 32), 256, 0, stream>>>(W_in2, Wt12 + (size_t)E * H, H, E);
    transpose_bf16<<<dim3(E / 32, E / 32), 256, 0, stream>>>(W_z, Wtzh, E, E);
    transpose_bf16<<<dim3(E / 32, E / 32), 256, 0, stream>>>(W_h, Wtzh + (size_t)E * E, E, E);
    transpose_bf16<<<dim3(H / 32, E / 32), 256, 0, stream>>>(W_out, Wto, E, H);

    // Merged input GEMM: N=4096 (W1|W2), split-silu epilogue -> xin / xskip
    gemm_bt<0><<<dim3(M / 128, 2 * E / 128), 256, 0, stream>>>(
        xb, Wt12, b_in1, b_in2, xin, xskip, 2 * E, H, M / 128, 0, 0);

    // Recurrent stage, chunked over S (rawzh overlays dead xb)
    for (int c = 0; c < NC; ++c) {
        const int row_off = c * CS;
        gemm_bt<4><<<dim3(MC / 128, 2 * E / 128), 256, 0, stream>>>(
            xin, Wtzh, b_z, b_h, rawzh, nullptr, 2 * E, E, CS / 128, S, row_off);
        scan_kernel<<<(B * E) / 64, 1024, 0, stream>>>(
            rawzh, xskip, carry, CS, S, row_off, c == 0);
    }

    // Output GEMM (full M), fp32 out
    gemm_bt<3><<<dim3(M / 128, H / 128), 256, 0, stream>>>(
        xskip, Wto, b_out, nullptr, (float*)d_out, nullptr, H, E, M / 128, 0, 0);
}

// Round 8
// 798.055 us; speedup vs baseline: 1.1626x; 1.1271x over previous
//
#include <hip/hip_runtime.h>
#include <hip/hip_bf16.h>

// Gramba (fp32 in / fp32 out): x_in = silu(x@W1+b1); x_skip = silu(x@W2+b2)
//         z = sigmoid(x_in@Wz+bz); h~ = x_in@Wh+bh
//         h = scan(h = (1-z)h + z*h~); out = (x_skip+h)@Wo + bo
// R8: coalesced LDS-staged epilogue for bf16 outputs (MODE 0/4) -- acc tile
// goes through a 128x144-padded LDS tile (2-way banks = free) and out as
// 16B dwordx4 stores, replacing 64 scattered 2B stores/thread. K-loop is
// R7's double-buffered vmcnt(4) pipeline with XOR-swizzled LDS (0 conflicts).
//
// Workspace layout (183 MiB):
//   [0,32)    rawzh chunk (bf16, 4096x4096)   [xb overlays [0,16) before use]
//   [32,33)   carry (fp32 h state, 4x2048)
//   [33,97)   xin   (bf16, 16384x2048)
//   [97,161)  xskip (bf16; scan overwrites with s = x_skip+h)
//   [161,165) Wt12  (bf16 [4096][512])
//   [165,181) Wtzh  (bf16 [4096][2048])
//   [181,183) Wto   (bf16 [512][2048])

typedef __bf16 bf16x8 __attribute__((ext_vector_type(8)));
typedef __bf16 bf16x4 __attribute__((ext_vector_type(4)));
typedef float  f32x4  __attribute__((ext_vector_type(4)));

#define DEVINL __device__ __forceinline__

DEVINL void async_ld16(const __bf16* g, __bf16* l) {
    __builtin_amdgcn_global_load_lds(
        (const __attribute__((address_space(1))) void*)g,
        (__attribute__((address_space(3))) void*)l, 16, 0, 0);
}

DEVINL float fsigmoid(float v) { return 1.0f / (1.0f + __expf(-v)); }

struct KLoopSM { __bf16 A[2][128 * 32]; __bf16 B[2][128 * 32]; };  // 32 KB

// MODE 0: dual split-silu -> bf16 out/out2 | MODE 3: fp32 out (old epilogue)
// MODE 4: bf16 out, dual bias split at 2048
template <int MODE>
__global__ __launch_bounds__(256)
void gemm_bt(const __bf16* __restrict__ A, const __bf16* __restrict__ Bt,
             const float* __restrict__ bias, const float* __restrict__ bias2,
             void* __restrict__ out, void* __restrict__ out2, int N, int K,
             int bps, int seg_stride, int row_off)
{
    __shared__ union SM {
        KLoopSM kl;
        __bf16 ct[128 * 144];   // 36 KB epilogue tile, row stride 144 (+16 pad)
    } sm;
    const int tid = threadIdx.x;
    const int bx = blockIdx.x;
    const int seg = bx / bps;
    const int within = bx - seg * bps;
    const int gm0 = row_off + seg * seg_stride + within * 128;  // A row base
    const int om0 = bx * 128;                                   // out row base
    const int n0 = blockIdx.y * 128;

    // Staging: 8KB tile = 512 x 16B chunks. Slot c holds global chunk
    // (row = c>>2, kc = (c&3) ^ ((c>>3)&3)) -- XOR swizzle, conflict-free.
    const int c0 = tid, c1 = tid + 256;
    const int r0 = c0 >> 2, k0 = (c0 & 3) ^ ((c0 >> 3) & 3);
    const int r1 = c1 >> 2, k1 = (c1 & 3) ^ ((c1 >> 3) & 3);
    const __bf16* Ag0 = A  + (size_t)(gm0 + r0) * K + k0 * 8;
    const __bf16* Ag1 = A  + (size_t)(gm0 + r1) * K + k1 * 8;
    const __bf16* Bg0 = Bt + (size_t)(n0 + r0) * K + k0 * 8;
    const __bf16* Bg1 = Bt + (size_t)(n0 + r1) * K + k1 * 8;

    const int lane = tid & 63;
    const int wave = tid >> 6;
    const int wrow = (wave >> 1) * 64;
    const int wcol = (wave & 1) * 64;
    const int quad = lane >> 4;
    const int r = lane & 15;
    const int swz = (quad ^ ((r >> 1) & 3)) * 8;

    f32x4 acc[4][4] = {};

    const int T = K >> 5;
    async_ld16(Ag0, sm.kl.A[0] + c0 * 8);
    async_ld16(Ag1, sm.kl.A[0] + c1 * 8);
    async_ld16(Bg0, sm.kl.B[0] + c0 * 8);
    async_ld16(Bg1, sm.kl.B[0] + c1 * 8);

    for (int t = 0; t < T; ++t) {
        const int cur = t & 1;
        if (t + 1 < T) {
            const int kt = (t + 1) << 5;
            async_ld16(Ag0 + kt, sm.kl.A[cur ^ 1] + c0 * 8);
            async_ld16(Ag1 + kt, sm.kl.A[cur ^ 1] + c1 * 8);
            async_ld16(Bg0 + kt, sm.kl.B[cur ^ 1] + c0 * 8);
            async_ld16(Bg1 + kt, sm.kl.B[cur ^ 1] + c1 * 8);
            asm volatile("s_waitcnt vmcnt(4)\n\ts_barrier" ::: "memory");
        } else {
            asm volatile("s_waitcnt vmcnt(0)\n\ts_barrier" ::: "memory");
        }

        const __bf16* ap = sm.kl.A[cur] + (wrow + r) * 32 + swz;
        const __bf16* bp = sm.kl.B[cur] + (wcol + r) * 32 + swz;
        bf16x8 af[4], bf_[4];
#pragma unroll
        for (int i = 0; i < 4; ++i) af[i] = *(const bf16x8*)(ap + i * 512);
#pragma unroll
        for (int i = 0; i < 4; ++i) bf_[i] = *(const bf16x8*)(bp + i * 512);
#pragma unroll
        for (int i = 0; i < 4; ++i)
#pragma unroll
            for (int j = 0; j < 4; ++j)
                acc[i][j] = __builtin_amdgcn_mfma_f32_16x16x32_bf16(
                    af[i], bf_[j], acc[i][j], 0, 0, 0);

        asm volatile("s_waitcnt lgkmcnt(0)\n\ts_barrier" ::: "memory");
    }

    // C/D layout (m89): col = lane&15, row = (lane>>4)*4 + reg
    if (MODE == 3) {
        // fp32 scalar epilogue (out GEMM only; K=2048 amortizes)
#pragma unroll
        for (int i = 0; i < 4; ++i)
#pragma unroll
            for (int j = 0; j < 4; ++j) {
                const int or0 = om0 + wrow + i * 16 + quad * 4;
                const int gc  = n0 + wcol + j * 16 + r;
                const float bv = bias[gc];
#pragma unroll
                for (int k = 0; k < 4; ++k)
                    ((float*)out)[(size_t)(or0 + k) * N + gc] = acc[i][j][k] + bv;
            }
    } else {
        // bf16: stage through padded LDS tile, then coalesced 16B stores.
        const bool lo = n0 < 2048;   // tile-uniform (n0 multiple of 128)
#pragma unroll
        for (int i = 0; i < 4; ++i)
#pragma unroll
            for (int j = 0; j < 4; ++j) {
                const int gc = n0 + wcol + j * 16 + r;
                const float bv = lo ? bias[gc] : bias2[gc - 2048];
#pragma unroll
                for (int k = 0; k < 4; ++k) {
                    const float v = acc[i][j][k] + bv;
                    const __bf16 o = (MODE == 0) ? (__bf16)(v * fsigmoid(v))
                                                 : (__bf16)v;
                    sm.ct[(wrow + i * 16 + quad * 4 + k) * 144 +
                          (wcol + j * 16 + r)] = o;
                }
            }
        __syncthreads();
        __bf16* dst;
        int cb;
        size_t stride;
        if (MODE == 0) {
            dst = lo ? (__bf16*)out : (__bf16*)out2;
            cb = lo ? n0 : n0 - 2048;
            stride = 2048;
        } else {
            dst = (__bf16*)out;
            cb = n0;
            stride = (size_t)N;
        }
        const int tr = tid >> 4;          // 0..15
        const int tc = (tid & 15) * 8;    // 8-col chunk
#pragma unroll
        for (int p = 0; p < 8; ++p) {
            const int row = p * 16 + tr;
            const bf16x8 vv = *(const bf16x8*)(sm.ct + row * 144 + tc);
            *(bf16x8*)(dst + (size_t)(om0 + row) * stride + cb + tc) = vv;
        }
    }
}

// Parallel minGRU scan over one chunk, on raw pre-activations:
// z = sigmoid(raw_z), b = z * raw_h, h = (1-z)h + b.
// raw is [B*CS][4096] (z cols 0..2047, h cols 2048..4095).
#define SCAN_WAVES 16
__global__ __launch_bounds__(1024)
void scan_kernel(const __bf16* __restrict__ raw, __bf16* __restrict__ xskip,
                 float* __restrict__ carry, int CS, int S, int t0, int first)
{
    __shared__ float Als[SCAN_WAVES][64];
    __shared__ float Bls[SCAN_WAVES][64];
    const int lane = threadIdx.x & 63;
    const int w = threadIdx.x >> 6;
    const int gpb = 2048 >> 6;
    const int batch = blockIdx.x / gpb;
    const int col = (blockIdx.x - batch * gpb) * 64 + lane;
    const int L = CS / SCAN_WAVES;             // 64
    const int tbeg = w * L;

    const size_t rbase = ((size_t)batch * CS + tbeg) * 4096 + col;

    float A = 1.0f, Bv = 0.0f;
    {
        size_t idx = rbase;
#pragma unroll 8
        for (int t = 0; t < L; ++t, idx += 4096) {
            const float z = fsigmoid((float)raw[idx]);
            const float b = z * (float)raw[idx + 2048];
            const float a = 1.0f - z;
            Bv = a * Bv + b;
            A *= a;
        }
    }
    Als[w][lane] = A;
    Bls[w][lane] = Bv;
    __syncthreads();

    const int ch = batch * 2048 + col;
    float h = first ? 0.0f : carry[ch];
    for (int s = 0; s < w; ++s)
        h = Als[s][lane] * h + Bls[s][lane];
    if (w == SCAN_WAVES - 1)
        carry[ch] = A * h + Bv;

    {
        size_t idx = rbase;
        size_t gidx = ((size_t)batch * S + t0 + tbeg) * 2048 + col;
#pragma unroll 8
        for (int t = 0; t < L; ++t, idx += 4096, gidx += 2048) {
            const float z = fsigmoid((float)raw[idx]);
            const float b = z * (float)raw[idx + 2048];
            h = (1.0f - z) * h + b;
            xskip[gidx] = (__bf16)((float)xskip[gidx] + h);
        }
    }
}

__global__ __launch_bounds__(256)
void conv_f32_bf16(const float* __restrict__ x, __bf16* __restrict__ y, int n4)
{
    const int i = blockIdx.x * 256 + threadIdx.x;
    if (i >= n4) return;
    const float4 v = ((const float4*)x)[i];
    bf16x4 o;
    o[0] = (__bf16)v.x; o[1] = (__bf16)v.y; o[2] = (__bf16)v.z; o[3] = (__bf16)v.w;
    ((bf16x4*)y)[i] = o;
}

// W[K][N] fp32 -> Wt[N][K] bf16
__global__ __launch_bounds__(256)
void transpose_bf16(const float* __restrict__ W, __bf16* __restrict__ Wt, int K, int N)
{
    __shared__ float tile[32][33];
    const int tx = threadIdx.x & 31;
    const int ty = threadIdx.x >> 5;
    const int nb = blockIdx.x * 32;
    const int kb = blockIdx.y * 32;
#pragma unroll
    for (int i = 0; i < 32; i += 8)
        tile[ty + i][tx] = W[(size_t)(kb + ty + i) * N + nb + tx];
    __syncthreads();
#pragma unroll
    for (int i = 0; i < 32; i += 8)
        Wt[(size_t)(nb + ty + i) * K + kb + tx] = (__bf16)tile[tx][ty + i];
}

extern "C" void kernel_launch(void* const* d_in, const int* in_sizes, int n_in,
                              void* d_out, int out_size, void* d_ws, size_t ws_size,
                              hipStream_t stream)
{
    const float* x     = (const float*)d_in[0];
    const float* W_in1 = (const float*)d_in[1];
    const float* b_in1 = (const float*)d_in[2];
    const float* W_in2 = (const float*)d_in[3];
    const float* b_in2 = (const float*)d_in[4];
    const float* W_z   = (const float*)d_in[5];
    const float* b_z   = (const float*)d_in[6];
    const float* W_h   = (const float*)d_in[7];
    const float* b_h   = (const float*)d_in[8];
    const float* W_out = (const float*)d_in[9];
    const float* b_out = (const float*)d_in[10];

    const int B = 4, S = 4096, H = 512, E = 2048;
    const int M = B * S;        // 16384
    const int CS = 1024;        // chunk length
    const int NC = S / CS;      // 4 chunks
    const int MC = B * CS;      // 4096 rows per chunk

    const size_t MiB = 1024 * 1024;
    const size_t NEEDED = 183 * MiB;
    if (ws_size < NEEDED) return;

    char* ws = (char*)d_ws;
    __bf16* xb    = (__bf16*)(ws + 0);        // overlaid by rawzh after use
    __bf16* rawzh = (__bf16*)(ws + 0);
    float*  carry = (float*) (ws + 32 * MiB);
    __bf16* xin   = (__bf16*)(ws + 33 * MiB);
    __bf16* xskip = (__bf16*)(ws + 97 * MiB);
    __bf16* Wt12  = (__bf16*)(ws + 161 * MiB);
    __bf16* Wtzh  = (__bf16*)(ws + 165 * MiB);
    __bf16* Wto   = (__bf16*)(ws + 181 * MiB);

    conv_f32_bf16<<<(M * H / 4 + 255) / 256, 256, 0, stream>>>(x, xb, M * H / 4);
    transpose_bf16<<<dim3(E / 32, H / 32), 256, 0, stream>>>(W_in1, Wt12, H, E);
    transpose_bf16<<<dim3(E / 32, H / 32), 256, 0, stream>>>(W_in2, Wt12 + (size_t)E * H, H, E);
    transpose_bf16<<<dim3(E / 32, E / 32), 256, 0, stream>>>(W_z, Wtzh, E, E);
    transpose_bf16<<<dim3(E / 32, E / 32), 256, 0, stream>>>(W_h, Wtzh + (size_t)E * E, E, E);
    transpose_bf16<<<dim3(H / 32, E / 32), 256, 0, stream>>>(W_out, Wto, E, H);

    // Merged input GEMM: N=4096 (W1|W2), split-silu epilogue -> xin / xskip
    gemm_bt<0><<<dim3(M / 128, 2 * E / 128), 256, 0, stream>>>(
        xb, Wt12, b_in1, b_in2, xin, xskip, 2 * E, H, M / 128, 0, 0);

    // Recurrent stage, chunked over S (rawzh overlays dead xb)
    for (int c = 0; c < NC; ++c) {
        const int row_off = c * CS;
        gemm_bt<4><<<dim3(MC / 128, 2 * E / 128), 256, 0, stream>>>(
            xin, Wtzh, b_z, b_h, rawzh, nullptr, 2 * E, E, CS / 128, S, row_off);
        scan_kernel<<<(B * E) / 64, 1024, 0, stream>>>(
            rawzh, xskip, carry, CS, S, row_off, c == 0);
    }

    // Output GEMM (full M), fp32 out
    gemm_bt<3><<<dim3(M / 128, H / 128), 256, 0, stream>>>(
        xskip, Wto, b_out, nullptr, (float*)d_out, nullptr, H, E, M / 128, 0, 0);
}